// Round 6
// baseline (174.869 us; speedup 1.0000x reference)
//
#include <hip/hip_runtime.h>

// BlockResMLP mixer, fused single kernel — swapped-MFMA, K=32-only, low-VGPR,
// with explicit next-block weight prefetch (cur/nxt double-buffer, round-0 pattern).
// 16384 rows x 1024 cols fp32. Two layers of per-block MLP(32->64 ELU ->32)+residual,
// 32x32 cross-block transpose between layers (gap=1 then gap=32).
//
// GEMM1 computed SWAPPED (hT = mfma(A=W1^T-frag, B=x^T-frag)) so each lane holds
// h[16c+4q+r][t]. GEMM2 (yT = W2^T @ hT) chains with ZERO data movement: the K=32
// B-fragment over chunk-pair e is the register CONCATENATION {av[2e], av[2e+1]}
// under feature(k=8q+j) = 32e + 16*(j>=4) + 4q + (j&3); the W2 pack permutes
// features identically. Biases fold into MFMA C (loaded point-of-use, L1-hot).
// Inter-layer transpose via one 32KB tile [colblk][row][k] + XOR swizzle.
//
// Register-pressure ledger (hard-won):
//   r3: __launch_bounds__(256,4) -> 64-VGPR cap -> 80MB spill, 0.085% MfmaUtil.
//   r4: no hint -> 132 VGPR -> crosses 128 occupancy step (4->2 waves/SIMD), 85us.
//   r5: point-of-use loads, (256,2) -> 108 VGPR, 62us — but weight-load latency
//       exposed on the serial path (no prefetch). This version: WFrags cur/nxt
//       double-buffer (w1[4]+w2[4] only; biases excluded), issued at top of each
//       u-iteration. Must stay <=128 VGPR with zero scratch.

typedef unsigned short u16t;
typedef __bf16 bf16x8 __attribute__((ext_vector_type(8)));
typedef __bf16 bf16x4 __attribute__((ext_vector_type(4)));
typedef float f32x4 __attribute__((ext_vector_type(4)));

__device__ __forceinline__ u16t f2b(float f) {           // fp32 -> bf16 RNE (pack kernel)
  union { float f; unsigned u; } v; v.f = f;
  unsigned r = v.u + 0x7FFFu + ((v.u >> 16) & 1u);
  return (u16t)(r >> 16);
}
__device__ __forceinline__ float b2f(u16t h) {
  union { unsigned u; float f; } v; v.u = ((unsigned)h) << 16;
  return v.f;
}
__device__ __forceinline__ u16t f2b_hw(float f) {        // HW v_cvt (RNE) path
  union { __bf16 h; u16t u; } v; v.h = (__bf16)f;
  return v.u;
}
__device__ __forceinline__ float elu(float v) {
  return fmaxf(v, 0.f) + fminf(__expf(v) - 1.f, 0.f);
}

// Tile swizzle: XOR bits 2..5 with (bits 6..9 ^ bits 10..13). Keeps 8B groups
// contiguous+aligned (vector reads OK), spreads strided scalar stores across banks.
__device__ __forceinline__ int swz(int idx) {
  return idx ^ ((((idx >> 6) ^ (idx >> 10)) & 15) << 2);
}

// ---------------- weight pack: fp32 -> bf16 MFMA fragment order ----------------
// pW1[L][n][c][lane][j]  : W1[n][k=q*8+j][c*16+t]                       (A-frag, K=32)
// pW2[L][n][f][lane][j]  : f = e*2+c2;
//     j<4 : W2[n][32e      + 4q + j    ][16c2+t]
//     j>=4: W2[n][32e + 16 + 4q + (j-4)][16c2+t]                        (A-frag, K=32, paired chunks)
__global__ __launch_bounds__(256) void pack_weights(
    const float* __restrict__ W1a, const float* __restrict__ W2a,
    const float* __restrict__ W1b, const float* __restrict__ W2b,
    u16t* __restrict__ pW1, u16t* __restrict__ pW2) {
  int tidg = blockIdx.x * 256 + threadIdx.x;   // 0..32767
  int tensor = tidg >> 14;                     // 0 = W1, 1 = W2
  int r  = tidg & 16383;
  int L  = r >> 13;
  int r2 = r & 8191;
  int n    = r2 >> 8;
  int f    = (r2 >> 6) & 3;
  int lane = r2 & 63;
  int q = lane >> 4, t = lane & 15;

  union { u16t us[8]; uint4 v; } w;
  if (tensor == 0) {
    const float* src = L ? W1b : W1a;
#pragma unroll
    for (int j = 0; j < 8; j++)
      w.us[j] = f2b(src[n * 2048 + (q * 8 + j) * 64 + f * 16 + t]);
    *(uint4*)(pW1 + (size_t)((((L * 32 + n) * 4 + f) * 64 + lane) * 8)) = w.v;
  } else {
    const float* src = L ? W2b : W2a;
    int e = f >> 1, c2 = f & 1;
#pragma unroll
    for (int j = 0; j < 8; j++) {
      int feat = 32 * e + (j >= 4 ? 16 : 0) + 4 * q + (j & 3);
      w.us[j] = f2b(src[n * 2048 + feat * 32 + 16 * c2 + t]);
    }
    *(uint4*)(pW2 + (size_t)((((L * 32 + n) * 4 + f) * 64 + lane) * 8)) = w.v;
  }
}

// ---------------- per-layer compute (8 blocks per wave) ----------------
struct WFrags {
  bf16x8 w1[4];   // GEMM1 col-chunks c=0..3
  bf16x8 w2[4];   // GEMM2 frags f=e*2+c2
};

__device__ __forceinline__ void load_w(WFrags& F, const u16t* __restrict__ pW1,
                                       const u16t* __restrict__ pW2, int base) {
#pragma unroll
  for (int f = 0; f < 4; f++) {
    F.w1[f] = *(const bf16x8*)(pW1 + base + f * 512);
    F.w2[f] = *(const bf16x8*)(pW2 + base + f * 512);
  }
}

// afr[u]: x-frag, lane (q,t) holds x[t][8q+j] of block n0+u.
// Writes y[t][32n + cc] (cc = 16c2+4q+r) to tile at logical idx = cc*512 + t*32 + n.
template <int L>
__device__ __forceinline__ void compute_layer(
    const bf16x8* __restrict__ afr, u16t* __restrict__ tile,
    const u16t* __restrict__ pW1, const u16t* __restrict__ pW2,
    const float* __restrict__ b1, const float* __restrict__ b2,
    int n0, int lane, int q, int t, const bf16x8* __restrict__ ifr) {
  const int base0 = ((L * 32 + n0) * 4) * 512 + lane * 8;
  WFrags cur, nxt;
  load_w(cur, pW1, pW2, base0);
#pragma unroll
  for (int u = 0; u < 8; u++) {
    const int n = n0 + u;
    // prefetch next block's weights at TOP of iteration: full-iteration latency cover
    if (u < 7) load_w(nxt, pW1, pW2, base0 + (u + 1) * 4 * 512);

    // GEMM1 swapped, chunk-paired; biases point-of-use as MFMA C.
    bf16x8 bfrag[2];
#pragma unroll
    for (int e = 0; e < 2; e++) {
      f32x4 b1lo = *(const f32x4*)(b1 + n * 64 + (2 * e) * 16 + q * 4);
      f32x4 b1hi = *(const f32x4*)(b1 + n * 64 + (2 * e + 1) * 16 + q * 4);
      f32x4 h0 = __builtin_amdgcn_mfma_f32_16x16x32_bf16(cur.w1[2 * e],     afr[u], b1lo, 0, 0, 0);
      f32x4 h1 = __builtin_amdgcn_mfma_f32_16x16x32_bf16(cur.w1[2 * e + 1], afr[u], b1hi, 0, 0, 0);
      bf16x4 a0, a1;
#pragma unroll
      for (int r = 0; r < 4; r++) {
        a0[r] = (__bf16)elu(h0[r]);
        a1[r] = (__bf16)elu(h1[r]);
      }
      bfrag[e] = __builtin_shufflevector(a0, a1, 0, 1, 2, 3, 4, 5, 6, 7);
    }

    // GEMM2 swapped: yT = W2^T @ hT; residual via identity-A MFMA; b2 via C.
#pragma unroll
    for (int c2 = 0; c2 < 2; c2++) {
      f32x4 b2v = *(const f32x4*)(b2 + n * 32 + c2 * 16 + q * 4);
      f32x4 acc = __builtin_amdgcn_mfma_f32_16x16x32_bf16(ifr[c2], afr[u], b2v, 0, 0, 0);
#pragma unroll
      for (int e = 0; e < 2; e++)
        acc = __builtin_amdgcn_mfma_f32_16x16x32_bf16(cur.w2[e * 2 + c2], bfrag[e], acc, 0, 0, 0);
#pragma unroll
      for (int r = 0; r < 4; r++) {
        int cc  = c2 * 16 + q * 4 + r;          // out col within block
        int idx = cc * 512 + t * 32 + n;        // [colblk][row][k=n]
        tile[swz(idx)] = f2b_hw(acc[r]);
      }
    }
    cur = nxt;
  }
}

__global__ __launch_bounds__(256, 2) void mixer_kernel(
    const float* __restrict__ x,
    const float* __restrict__ b1a, const float* __restrict__ b2a,
    const float* __restrict__ b1b, const float* __restrict__ b2b,
    const u16t* __restrict__ pW1, const u16t* __restrict__ pW2,
    float* __restrict__ out) {
  __shared__ u16t tile[16384];                  // 32 KB: [colblk 0..31][row 0..15][k 0..31]

  const int tid  = threadIdx.x;
  const int wave = tid >> 6, lane = tid & 63;
  const int q = lane >> 4, t = lane & 15;
  const int r0 = blockIdx.x * 16;
  const int n0 = wave * 8;

  // identity A-frags for the swapped residual MFMA: A[m=t][k=8q+j] = (8q+j == 16c2+t)
  bf16x8 ifr[2];
#pragma unroll
  for (int c2 = 0; c2 < 2; c2++) {
    union { u16t us[8]; bf16x8 v; } w;
#pragma unroll
    for (int j = 0; j < 8; j++)
      w.us[j] = ((q * 8 + j) == (c2 * 16 + t)) ? (u16t)0x3F80 : (u16t)0;
    ifr[c2] = w.v;
  }

  // ---- layer 1 input frags straight from global ----
  bf16x8 afr[8];
#pragma unroll
  for (int u = 0; u < 8; u++) {
    const float* gp = x + (size_t)(r0 + t) * 1024 + (n0 + u) * 32 + q * 8;
    float4 v0 = *(const float4*)gp;
    float4 v1 = *(const float4*)(gp + 4);
    union { __bf16 h[8]; bf16x8 v; } a;
    a.h[0] = (__bf16)v0.x; a.h[1] = (__bf16)v0.y; a.h[2] = (__bf16)v0.z; a.h[3] = (__bf16)v0.w;
    a.h[4] = (__bf16)v1.x; a.h[5] = (__bf16)v1.y; a.h[6] = (__bf16)v1.z; a.h[7] = (__bf16)v1.w;
    afr[u] = a.v;
  }

  compute_layer<0>(afr, tile, pW1, pW2, b1a, b2a, n0, lane, q, t, ifr);
  __syncthreads();

  // ---- layer 2 gather: z_n2[t][8q+j] = y1[t][(8q+j)*32 + n2] -> two ds_read_b64 per u ----
#pragma unroll
  for (int u = 0; u < 8; u++) {
    const int n2 = n0 + u;
    int idx = n2 * 512 + t * 32 + q * 8;
    union { ushort4 h[2]; bf16x8 v; } a;
    a.h[0] = *(const ushort4*)&tile[swz(idx)];
    a.h[1] = *(const ushort4*)&tile[swz(idx + 4)];
    afr[u] = a.v;
  }
  __syncthreads();                              // gathers done before tile is overwritten

  compute_layer<1>(afr, tile, pW1, pW2, b1b, b2b, n0, lane, q, t, ifr);
  __syncthreads();

  // ---- output: out[m][cc*32+n2] = y2[m][32*n2+cc]; tile layout makes this 4-contig ----
#pragma unroll
  for (int i = 0; i < 16; i++) {
    int c  = tid >> 3;
    int n2 = (tid & 7) * 4;
    int idx = c * 512 + i * 32 + n2;
    ushort4 hv = *(const ushort4*)&tile[swz(idx)];
    float4 o;
    o.x = b2f(hv.x); o.y = b2f(hv.y); o.z = b2f(hv.z); o.w = b2f(hv.w);
    *(float4*)(out + (size_t)(r0 + i) * 1024 + tid * 4) = o;
  }
}

extern "C" void kernel_launch(void* const* d_in, const int* in_sizes, int n_in,
                              void* d_out, int out_size, void* d_ws, size_t ws_size,
                              hipStream_t stream) {
  const float* x   = (const float*)d_in[0];
  const float* W1a = (const float*)d_in[1];
  const float* b1a = (const float*)d_in[2];
  const float* W2a = (const float*)d_in[3];
  const float* b2a = (const float*)d_in[4];
  const float* W1b = (const float*)d_in[5];
  const float* b1b = (const float*)d_in[6];
  const float* W2b = (const float*)d_in[7];
  const float* b2b = (const float*)d_in[8];
  float* out = (float*)d_out;

  u16t* pW1 = (u16t*)d_ws;
  u16t* pW2 = pW1 + 131072;   // 256 KB each, 512 KB total in d_ws

  const int rows = in_sizes[0] / 1024;

  pack_weights<<<128, 256, 0, stream>>>(W1a, W2a, W1b, W2b, pW1, pW2);
  mixer_kernel<<<rows / 16, 256, 0, stream>>>(x, b1a, b2a, b1b, b2b, pW1, pW2, out);
}

// Round 7
// 161.345 us; speedup vs baseline: 1.0838x; 1.0838x over previous
//
#include <hip/hip_runtime.h>

// BlockResMLP mixer — swapped-MFMA, K=32-only, 32-rows/WG, staged-coalesced x.
// 16384 rows x 1024 cols fp32. Two layers of per-block MLP(32->64 ELU ->32)+residual,
// 32x32 cross-block transpose between layers (gap=1 then gap=32).
//
// Structure (r7): WG = 512 thr (8 waves), 32 rows, 64KB LDS tile [A][row][B]
// (idx = A*1024 + row*32 + B; col omega <-> (A=omega>>5, B=omega&31)).
//   stage-in (coalesced f4 loads -> bf16 tile)  | fixes the 4KB-stride scatter
//   gather L1 afr (8x ds_read_b64 pairs)        | unified path, conflict-free via swz
//   compute L1 (4 blocks x 2 row-groups/wave)   | weights loaded ONCE per block,
//   gather L2 (identical addressing)            |   reused for 2 row-groups:
//   compute L2                                  |   L2 weight traffic halved
//   output (coalesced f4 stores)
// GEMM1 swapped (hT = mfma(W1^T, x^T)): lane holds h[16c+4q+r][t]; GEMM2 B-frag is
// the register CONCAT {av[2e],av[2e+1]} under feature(k=8q+j)=32e+16*(j>=4)+4q+(j&3)
// (W2 pack permuted identically). Residual via identity-A MFMA; biases in MFMA C.
//
// Register ledger: r3 (256,4)->64-cap->spill; r4 no-hint->132->2 waves/SIMD; r5
// (256,2)->108, 62us; r6 cur/nxt copy prefetch -> REGRESSED (serial v_movs).
// Empirical cap rule: cap = 512/(2*arg) -> (512,2) pins <=128. No prefetch copies.

typedef unsigned short u16t;
typedef __bf16 bf16x8 __attribute__((ext_vector_type(8)));
typedef __bf16 bf16x4 __attribute__((ext_vector_type(4)));
typedef float f32x4 __attribute__((ext_vector_type(4)));

__device__ __forceinline__ u16t f2b(float f) {           // fp32 -> bf16 RNE (pack kernel)
  union { float f; unsigned u; } v; v.f = f;
  unsigned r = v.u + 0x7FFFu + ((v.u >> 16) & 1u);
  return (u16t)(r >> 16);
}
__device__ __forceinline__ float b2f(u16t h) {
  union { unsigned u; float f; } v; v.u = ((unsigned)h) << 16;
  return v.f;
}
__device__ __forceinline__ u16t f2b_hw(float f) {
  union { __bf16 h; u16t u; } v; v.h = (__bf16)f;
  return v.u;
}
__device__ __forceinline__ float elu(float v) {
  return fmaxf(v, 0.f) + fminf(__expf(v) - 1.f, 0.f);
}

// Tile swizzle for the 32K-u16 tile: XOR bits 2..5 with (bits 6..9 ^ bits 10..13).
// Preserves 8B groups (ushort4 reads/writes stay aligned); spreads both the
// strided compute-writes and the gather reads across banks (~2-way max).
__device__ __forceinline__ int swz(int idx) {
  return idx ^ ((((idx >> 6) ^ (idx >> 10)) & 15) << 2);
}

// ---------------- weight pack: fp32 -> bf16 MFMA fragment order ----------------
// pW1[L][n][c][lane][j]  : W1[n][k=q*8+j][c*16+t]                       (A-frag, K=32)
// pW2[L][n][f][lane][j]  : f = e*2+c2;
//     j<4 : W2[n][32e      + 4q + j    ][16c2+t]
//     j>=4: W2[n][32e + 16 + 4q + (j-4)][16c2+t]                        (A-frag, K=32, paired)
__global__ __launch_bounds__(256) void pack_weights(
    const float* __restrict__ W1a, const float* __restrict__ W2a,
    const float* __restrict__ W1b, const float* __restrict__ W2b,
    u16t* __restrict__ pW1, u16t* __restrict__ pW2) {
  int tidg = blockIdx.x * 256 + threadIdx.x;   // 0..32767
  int tensor = tidg >> 14;                     // 0 = W1, 1 = W2
  int r  = tidg & 16383;
  int L  = r >> 13;
  int r2 = r & 8191;
  int n    = r2 >> 8;
  int f    = (r2 >> 6) & 3;
  int lane = r2 & 63;
  int q = lane >> 4, t = lane & 15;

  union { u16t us[8]; uint4 v; } w;
  if (tensor == 0) {
    const float* src = L ? W1b : W1a;
#pragma unroll
    for (int j = 0; j < 8; j++)
      w.us[j] = f2b(src[n * 2048 + (q * 8 + j) * 64 + f * 16 + t]);
    *(uint4*)(pW1 + (size_t)((((L * 32 + n) * 4 + f) * 64 + lane) * 8)) = w.v;
  } else {
    const float* src = L ? W2b : W2a;
    int e = f >> 1, c2 = f & 1;
#pragma unroll
    for (int j = 0; j < 8; j++) {
      int feat = 32 * e + (j >= 4 ? 16 : 0) + 4 * q + (j & 3);
      w.us[j] = f2b(src[n * 2048 + feat * 32 + 16 * c2 + t]);
    }
    *(uint4*)(pW2 + (size_t)((((L * 32 + n) * 4 + f) * 64 + lane) * 8)) = w.v;
  }
}

// ---------------- gather: afr[b*2+rg] for blocks w0..w0+3, row-groups 0..1 ----
__device__ __forceinline__ void gather_afr(bf16x8* __restrict__ afr,
                                           const u16t* __restrict__ tile,
                                           int w0, int q, int t) {
#pragma unroll
  for (int b = 0; b < 4; b++) {
#pragma unroll
    for (int rg = 0; rg < 2; rg++) {
      const int n = w0 + b;
      const int row = rg * 16 + t;
      const int idx = n * 1024 + row * 32 + q * 8;
      union { ushort4 h[2]; bf16x8 v; } a;
      a.h[0] = *(const ushort4*)&tile[swz(idx)];
      a.h[1] = *(const ushort4*)&tile[swz(idx + 4)];
      afr[b * 2 + rg] = a.v;
    }
  }
}

// ---------------- per-layer compute (4 blocks x 2 row-groups per wave) --------
// Writes y[row][32n+cc] (cc = 16c2+4q+r) at tile idx = cc*1024 + row*32 + n.
template <int L>
__device__ __forceinline__ void compute_layer(
    const bf16x8* __restrict__ afr, u16t* __restrict__ tile,
    const u16t* __restrict__ pW1, const u16t* __restrict__ pW2,
    const float* __restrict__ b1, const float* __restrict__ b2,
    int w0, int lane, int q, int t, const bf16x8* __restrict__ ifr) {
#pragma unroll
  for (int b = 0; b < 4; b++) {
    const int n = w0 + b;
    const int wbase = ((L * 32 + n) * 4) * 512 + lane * 8;

    // weights loaded ONCE per block, reused for both row-groups (12 MFMAs / 8KB)
    bf16x8 w1f[4], w2f[4];
#pragma unroll
    for (int f = 0; f < 4; f++) {
      w1f[f] = *(const bf16x8*)(pW1 + wbase + f * 512);
      w2f[f] = *(const bf16x8*)(pW2 + wbase + f * 512);
    }

#pragma unroll
    for (int rg = 0; rg < 2; rg++) {
      const bf16x8 a = afr[b * 2 + rg];

      // GEMM1 swapped, chunk-paired; b1 as MFMA C (point-of-use, L1-hot).
      bf16x8 bfrag[2];
#pragma unroll
      for (int e = 0; e < 2; e++) {
        f32x4 b1lo = *(const f32x4*)(b1 + n * 64 + (2 * e) * 16 + q * 4);
        f32x4 b1hi = *(const f32x4*)(b1 + n * 64 + (2 * e + 1) * 16 + q * 4);
        f32x4 h0 = __builtin_amdgcn_mfma_f32_16x16x32_bf16(w1f[2 * e],     a, b1lo, 0, 0, 0);
        f32x4 h1 = __builtin_amdgcn_mfma_f32_16x16x32_bf16(w1f[2 * e + 1], a, b1hi, 0, 0, 0);
        bf16x4 a0, a1;
#pragma unroll
        for (int r = 0; r < 4; r++) {
          a0[r] = (__bf16)elu(h0[r]);
          a1[r] = (__bf16)elu(h1[r]);
        }
        bfrag[e] = __builtin_shufflevector(a0, a1, 0, 1, 2, 3, 4, 5, 6, 7);
      }

      // GEMM2 swapped + identity-residual + b2 via C.
#pragma unroll
      for (int c2 = 0; c2 < 2; c2++) {
        f32x4 b2v = *(const f32x4*)(b2 + n * 32 + c2 * 16 + q * 4);
        f32x4 acc = __builtin_amdgcn_mfma_f32_16x16x32_bf16(ifr[c2], a, b2v, 0, 0, 0);
#pragma unroll
        for (int e = 0; e < 2; e++)
          acc = __builtin_amdgcn_mfma_f32_16x16x32_bf16(w2f[e * 2 + c2], bfrag[e], acc, 0, 0, 0);
#pragma unroll
        for (int r = 0; r < 4; r++) {
          int cc  = c2 * 16 + q * 4 + r;
          int idx = cc * 1024 + (rg * 16 + t) * 32 + n;
          tile[swz(idx)] = f2b_hw(acc[r]);
        }
      }
    }
  }
}

__global__ __launch_bounds__(512, 2) void mixer_kernel(
    const float* __restrict__ x,
    const float* __restrict__ b1a, const float* __restrict__ b2a,
    const float* __restrict__ b1b, const float* __restrict__ b2b,
    const u16t* __restrict__ pW1, const u16t* __restrict__ pW2,
    float* __restrict__ out) {
  __shared__ u16t tile[32768];                  // 64 KB: [A 0..31][row 0..31][B 0..31]

  const int tid  = threadIdx.x;
  const int wave = tid >> 6, lane = tid & 63;
  const int q = lane >> 4, t = lane & 15;
  const int r0 = blockIdx.x * 32;
  const int w0 = wave * 4;                      // this wave's first block

  // identity A-frags for the swapped residual MFMA: A[m=t][k=8q+j] = (8q+j == 16c2+t)
  bf16x8 ifr[2];
#pragma unroll
  for (int c2 = 0; c2 < 2; c2++) {
    union { u16t us[8]; bf16x8 v; } w;
#pragma unroll
    for (int j = 0; j < 8; j++)
      w.us[j] = ((q * 8 + j) == (c2 * 16 + t)) ? (u16t)0x3F80 : (u16t)0;
    ifr[c2] = w.v;
  }

  // ---- stage-in: coalesced f4 loads -> bf16 tile (col omega -> A=omega>>5, B=omega&31) ----
#pragma unroll
  for (int i = 0; i < 16; i++) {
    int e = i * 512 + tid;
    int row = e >> 8, c4 = e & 255;             // col = 4*c4
    float4 v = *(const float4*)(x + (size_t)(r0 + row) * 1024 + c4 * 4);
    ushort4 hv;
    hv.x = f2b_hw(v.x); hv.y = f2b_hw(v.y); hv.z = f2b_hw(v.z); hv.w = f2b_hw(v.w);
    int idx = (c4 >> 3) * 1024 + row * 32 + 4 * (c4 & 7);
    *(ushort4*)&tile[swz(idx)] = hv;
  }
  __syncthreads();

  // ---- layer 1 ----
  bf16x8 afr[8];
  gather_afr(afr, tile, w0, q, t);
  __syncthreads();                              // all gathers done before overwrite
  compute_layer<0>(afr, tile, pW1, pW2, b1a, b2a, w0, lane, q, t, ifr);
  __syncthreads();

  // ---- layer 2 (identical gather addressing = the 32x32 transpose) ----
  gather_afr(afr, tile, w0, q, t);
  __syncthreads();
  compute_layer<1>(afr, tile, pW1, pW2, b1b, b2b, w0, lane, q, t, ifr);
  __syncthreads();

  // ---- output: out col = 32A + B; coalesced f4 stores ----
#pragma unroll
  for (int i = 0; i < 16; i++) {
    int e = i * 512 + tid;
    int row = e >> 8, g = e & 255;
    int idx = (g >> 3) * 1024 + row * 32 + 4 * (g & 7);
    ushort4 hv = *(const ushort4*)&tile[swz(idx)];
    float4 o;
    o.x = b2f(hv.x); o.y = b2f(hv.y); o.z = b2f(hv.z); o.w = b2f(hv.w);
    *(float4*)(out + (size_t)(r0 + row) * 1024 + 4 * g) = o;
  }
}

extern "C" void kernel_launch(void* const* d_in, const int* in_sizes, int n_in,
                              void* d_out, int out_size, void* d_ws, size_t ws_size,
                              hipStream_t stream) {
  const float* x   = (const float*)d_in[0];
  const float* W1a = (const float*)d_in[1];
  const float* b1a = (const float*)d_in[2];
  const float* W2a = (const float*)d_in[3];
  const float* b2a = (const float*)d_in[4];
  const float* W1b = (const float*)d_in[5];
  const float* b1b = (const float*)d_in[6];
  const float* W2b = (const float*)d_in[7];
  const float* b2b = (const float*)d_in[8];
  float* out = (float*)d_out;

  u16t* pW1 = (u16t*)d_ws;
  u16t* pW2 = pW1 + 131072;   // 256 KB each, 512 KB total in d_ws

  const int rows = in_sizes[0] / 1024;

  pack_weights<<<128, 256, 0, stream>>>(W1a, W2a, W1b, W2b, pW1, pW2);
  mixer_kernel<<<rows / 32, 512, 0, stream>>>(x, b1a, b2a, b1b, b2b, pW1, pW2, out);
}